// Round 2
// baseline (585.719 us; speedup 1.0000x reference)
//
#include <hip/hip_runtime.h>

#define HW 4096
#define NC 96
#define NB 4
#define MID 24
#define NOUT 256
#define BEPS 1e-5f

// ---------------------------------------------------------------------------
// Kernel 1: 1x1 conv projections  pr[b,o,n] = sum_c Wr[o,c]*rgb[b,c,n]
// grid: (HW/256, NB, 2)  block: 256
// ---------------------------------------------------------------------------
__launch_bounds__(256)
__global__ void k_proj(const float* __restrict__ rgb, const float* __restrict__ dep,
                       const float* __restrict__ Wr, const float* __restrict__ Wd,
                       float* __restrict__ pr, float* __restrict__ pd) {
  __shared__ float Wl[NC * NC];
  const int which = blockIdx.z;                // 0: rgb*Wr -> pr ; 1: dep*Wd -> pd
  const float* W = which ? Wd : Wr;
  const float* src = which ? dep : rgb;
  float* dst = which ? pd : pr;
  const int b = blockIdx.y;
  const int n = blockIdx.x * 256 + threadIdx.x;
  for (int i = threadIdx.x; i < NC * NC; i += 256) Wl[i] = W[i];
  __syncthreads();

  const float* sp = src + (size_t)b * NC * HW + n;
  float* dp = dst + (size_t)b * NC * HW + n;

  // two halves of 48 outputs each to keep VGPR pressure sane
  #pragma unroll
  for (int half = 0; half < 2; ++half) {
    float acc[48];
    #pragma unroll
    for (int o = 0; o < 48; ++o) acc[o] = 0.f;
    for (int c = 0; c < NC; ++c) {
      float x = sp[(size_t)c * HW];
      #pragma unroll
      for (int o = 0; o < 48; ++o) acc[o] += Wl[(half * 48 + o) * NC + c] * x;
    }
    #pragma unroll
    for (int o = 0; o < 48; ++o) dp[(size_t)(half * 48 + o) * HW] = acc[o];
  }
}

// ---------------------------------------------------------------------------
// Energy tile kernel. e[n,m] = (1/sqrt(C)) * sum_c pr[b,c,n]*pd[b,c,m]
// Tile: 128 n  x 64 m, 256 threads, 8x4 per-thread register tile.
// PASS 0: zpart[ntile][b][m] = sum_{n in tile} exp(e)
// PASS 1: spart[mtile][b][n] = sum_{m in tile} exp(e) * rZ[m]
// grid: (HW/64, HW/128, NB)
// ---------------------------------------------------------------------------
template <int PASS>
__launch_bounds__(256)
__global__ void k_energy(const float* __restrict__ pr, const float* __restrict__ pd,
                         const float* __restrict__ Zr, float* __restrict__ part) {
  __shared__ float Al[NC][128];   // pr tile  [c][n]  48 KB
  __shared__ float Bl[NC][64];    // pd tile  [c][m]  24 KB
  __shared__ float red[4][64];

  const int m0 = blockIdx.x * 64;
  const int n0 = blockIdx.y * 128;
  const int b  = blockIdx.z;
  const int tid = threadIdx.x;
  const int tx = tid & 15;        // m group: 4 columns each
  const int ty = tid >> 4;        // n group: 8 rows each

  const float* prb = pr + (size_t)b * NC * HW;
  const float* pdb = pd + (size_t)b * NC * HW;
  for (int r = tid; r < NC * 128; r += 256) {
    int c = r >> 7, n = r & 127;
    Al[c][n] = prb[(size_t)c * HW + n0 + n];
  }
  for (int r = tid; r < NC * 64; r += 256) {
    int c = r >> 6, m = r & 63;
    Bl[c][m] = pdb[(size_t)c * HW + m0 + m];
  }
  __syncthreads();

  float acc[8][4];
  #pragma unroll
  for (int i = 0; i < 8; ++i)
    #pragma unroll
    for (int j = 0; j < 4; ++j) acc[i][j] = 0.f;

  #pragma unroll 2
  for (int c = 0; c < NC; ++c) {
    float4 a0 = *(const float4*)&Al[c][ty * 8];
    float4 a1 = *(const float4*)&Al[c][ty * 8 + 4];
    float4 bv = *(const float4*)&Bl[c][tx * 4];
    float av[8] = {a0.x, a0.y, a0.z, a0.w, a1.x, a1.y, a1.z, a1.w};
    float bb[4] = {bv.x, bv.y, bv.z, bv.w};
    #pragma unroll
    for (int i = 0; i < 8; ++i)
      #pragma unroll
      for (int j = 0; j < 4; ++j) acc[i][j] += av[i] * bb[j];
  }

  constexpr float INV_SQRT_C = 0.10206207261596575f;  // 1/sqrt(96)

  if (PASS == 0) {
    // column sums of exp(e) over this n-tile
    float z4[4] = {0.f, 0.f, 0.f, 0.f};
    #pragma unroll
    for (int i = 0; i < 8; ++i)
      #pragma unroll
      for (int j = 0; j < 4; ++j) z4[j] += __expf(acc[i][j] * INV_SQRT_C);
    #pragma unroll
    for (int j = 0; j < 4; ++j) {
      z4[j] += __shfl_xor(z4[j], 16, 64);
      z4[j] += __shfl_xor(z4[j], 32, 64);
    }
    const int wv = tid >> 6;
    if ((tid & 63) < 16) {
      #pragma unroll
      for (int j = 0; j < 4; ++j) red[wv][tx * 4 + j] = z4[j];
    }
    __syncthreads();
    if (tid < 64) {
      float z = red[0][tid] + red[1][tid] + red[2][tid] + red[3][tid];
      part[((size_t)blockIdx.y * NB + b) * HW + m0 + tid] = z;
    }
  } else {
    // row sums of att over this m-tile
    float rz[4];
    #pragma unroll
    for (int j = 0; j < 4; ++j) rz[j] = Zr[(size_t)b * HW + m0 + tx * 4 + j];
    #pragma unroll
    for (int i = 0; i < 8; ++i) {
      float sv = 0.f;
      #pragma unroll
      for (int j = 0; j < 4; ++j) sv += __expf(acc[i][j] * INV_SQRT_C) * rz[j];
      sv += __shfl_xor(sv, 1, 64);
      sv += __shfl_xor(sv, 2, 64);
      sv += __shfl_xor(sv, 4, 64);
      sv += __shfl_xor(sv, 8, 64);
      if ((tid & 15) == 0)
        part[((size_t)blockIdx.x * NB + b) * HW + n0 + ty * 8 + i] = sv;
    }
  }
}

// ---------------------------------------------------------------------------
// Reductions of deterministic partials
// ---------------------------------------------------------------------------
__global__ void k_zred(const float* __restrict__ zpart, float* __restrict__ Zr) {
  int idx = blockIdx.x * 256 + threadIdx.x;  // over NB*HW
  float s = 0.f;
  for (int t = 0; t < 32; ++t) s += zpart[(size_t)t * NB * HW + idx];
  Zr[idx] = 1.0f / s;   // store reciprocal
}

__global__ void k_sred(const float* __restrict__ spart, float* __restrict__ sv) {
  int idx = blockIdx.x * 256 + threadIdx.x;  // over NB*HW
  float a = 0.f;
  for (int t = 0; t < 64; ++t) a += spart[(size_t)t * NB * HW + idx];
  sv[idx] = a;
}

// ---------------------------------------------------------------------------
// gap[b,c] = (1/HW) * [ sum_n (pr+pd)[b,c,n]*s[b,n]  +  sum_n (rgb+dep)[b,c,n] ]
// grid: (NC, NB), block 256
// ---------------------------------------------------------------------------
__launch_bounds__(256)
__global__ void k_gap(const float* __restrict__ pr, const float* __restrict__ pd,
                      const float* __restrict__ rgb, const float* __restrict__ dep,
                      const float* __restrict__ sv, float* __restrict__ gap) {
  const int c = blockIdx.x, b = blockIdx.y;
  const size_t off = ((size_t)b * NC + c) * HW;
  const float* prp = pr + off;
  const float* pdp = pd + off;
  const float* rp = rgb + off;
  const float* dp = dep + off;
  const float* sp = sv + (size_t)b * HW;
  float a1 = 0.f, a2 = 0.f;
  for (int n = threadIdx.x; n < HW; n += 256) {
    a1 += (prp[n] + pdp[n]) * sp[n];
    a2 += rp[n] + dp[n];
  }
  #pragma unroll
  for (int o = 32; o > 0; o >>= 1) {
    a1 += __shfl_down(a1, o, 64);
    a2 += __shfl_down(a2, o, 64);
  }
  __shared__ float r1[4], r2[4];
  const int wv = threadIdx.x >> 6;
  if ((threadIdx.x & 63) == 0) { r1[wv] = a1; r2[wv] = a2; }
  __syncthreads();
  if (threadIdx.x == 0) {
    float t1 = r1[0] + r1[1] + r1[2] + r1[3];
    float t2 = r2[0] + r2[1] + r2[2] + r2[3];
    gap[b * NC + c] = (t1 + t2) * (1.0f / HW);   // FIX: both terms get 1/HW
  }
}

// ---------------------------------------------------------------------------
// Tiny MLP + training-mode BatchNorm (over batch of 4) + ReLU, one block.
// ---------------------------------------------------------------------------
__launch_bounds__(256)
__global__ void k_mlp(const float* __restrict__ gap,
                      const float* __restrict__ Wm1, const float* __restrict__ g1,
                      const float* __restrict__ b1,
                      const float* __restrict__ Wm2, const float* __restrict__ g2,
                      const float* __restrict__ b2, float* __restrict__ out) {
  __shared__ float gl[NB * NC];
  __shared__ float h[NB * MID];
  __shared__ float h1r[NB * MID];
  __shared__ float h2[NB * NOUT];
  const int tid = threadIdx.x;
  for (int i = tid; i < NB * NC; i += 256) gl[i] = gap[i];
  __syncthreads();

  if (tid < NB * MID) {
    int b = tid / MID, j = tid % MID;
    float acc = 0.f;
    #pragma unroll
    for (int c = 0; c < NC; ++c) acc += gl[b * NC + c] * Wm1[j * NC + c];
    h[b * MID + j] = acc;
  }
  __syncthreads();

  if (tid < MID) {
    float x0 = h[0 * MID + tid], x1 = h[1 * MID + tid];
    float x2 = h[2 * MID + tid], x3 = h[3 * MID + tid];
    float mu = 0.25f * (x0 + x1 + x2 + x3);
    float d0 = x0 - mu, d1 = x1 - mu, d2 = x2 - mu, d3 = x3 - mu;
    float v = 0.25f * (d0 * d0 + d1 * d1 + d2 * d2 + d3 * d3);
    float sc = g1[tid] * rsqrtf(v + BEPS);
    float bb = b1[tid];
    h1r[0 * MID + tid] = fmaxf(d0 * sc + bb, 0.f);
    h1r[1 * MID + tid] = fmaxf(d1 * sc + bb, 0.f);
    h1r[2 * MID + tid] = fmaxf(d2 * sc + bb, 0.f);
    h1r[3 * MID + tid] = fmaxf(d3 * sc + bb, 0.f);
  }
  __syncthreads();

  for (int idx = tid; idx < NB * NOUT; idx += 256) {
    int b = idx >> 8, o = idx & 255;
    float acc = 0.f;
    #pragma unroll
    for (int j = 0; j < MID; ++j) acc += h1r[b * MID + j] * Wm2[o * MID + j];
    h2[b * NOUT + o] = acc;
  }
  __syncthreads();

  if (tid < NOUT) {
    float x0 = h2[0 * NOUT + tid], x1 = h2[1 * NOUT + tid];
    float x2 = h2[2 * NOUT + tid], x3 = h2[3 * NOUT + tid];
    float mu = 0.25f * (x0 + x1 + x2 + x3);
    float d0 = x0 - mu, d1 = x1 - mu, d2 = x2 - mu, d3 = x3 - mu;
    float v = 0.25f * (d0 * d0 + d1 * d1 + d2 * d2 + d3 * d3);
    float sc = g2[tid] * rsqrtf(v + BEPS);
    float bb = b2[tid];
    out[0 * NOUT + tid] = fmaxf(d0 * sc + bb, 0.f);
    out[1 * NOUT + tid] = fmaxf(d1 * sc + bb, 0.f);
    out[2 * NOUT + tid] = fmaxf(d2 * sc + bb, 0.f);
    out[3 * NOUT + tid] = fmaxf(d3 * sc + bb, 0.f);
  }
}

// ---------------------------------------------------------------------------
extern "C" void kernel_launch(void* const* d_in, const int* in_sizes, int n_in,
                              void* d_out, int out_size, void* d_ws, size_t ws_size,
                              hipStream_t stream) {
  const float* rgb   = (const float*)d_in[0];
  const float* dep   = (const float*)d_in[1];
  const float* Wd    = (const float*)d_in[2];
  const float* Wr    = (const float*)d_in[3];
  const float* Wm1   = (const float*)d_in[4];
  const float* bn1_g = (const float*)d_in[5];
  const float* bn1_b = (const float*)d_in[6];
  const float* Wm2   = (const float*)d_in[7];
  const float* bn2_g = (const float*)d_in[8];
  const float* bn2_b = (const float*)d_in[9];
  float* out = (float*)d_out;

  float* ws = (float*)d_ws;
  float* pr    = ws;                       // NB*NC*HW
  float* pd    = pr + (size_t)NB * NC * HW;
  float* zpart = pd + (size_t)NB * NC * HW;         // 32 * NB * HW
  float* Zr    = zpart + (size_t)32 * NB * HW;      // NB * HW
  float* spart = Zr + (size_t)NB * HW;              // 64 * NB * HW
  float* sv    = spart + (size_t)64 * NB * HW;      // NB * HW
  float* gap   = sv + (size_t)NB * HW;              // NB * NC

  k_proj<<<dim3(HW / 256, NB, 2), 256, 0, stream>>>(rgb, dep, Wr, Wd, pr, pd);
  k_energy<0><<<dim3(HW / 64, HW / 128, NB), 256, 0, stream>>>(pr, pd, nullptr, zpart);
  k_zred<<<dim3(NB * HW / 256), 256, 0, stream>>>(zpart, Zr);
  k_energy<1><<<dim3(HW / 64, HW / 128, NB), 256, 0, stream>>>(pr, pd, Zr, spart);
  k_sred<<<dim3(NB * HW / 256), 256, 0, stream>>>(spart, sv);
  k_gap<<<dim3(NC, NB), 256, 0, stream>>>(pr, pd, rgb, dep, sv, gap);
  k_mlp<<<1, 256, 0, stream>>>(gap, Wm1, bn1_g, bn1_b, Wm2, bn2_g, bn2_b, out);
}

// Round 3
// 142.210 us; speedup vs baseline: 4.1187x; 4.1187x over previous
//
#include <hip/hip_runtime.h>

#define HW 4096
#define NC 96
#define NB 4
#define MID 24
#define NOUT 256
#define BEPS 1e-5f
#define SCALE_E 0.10206207261596575f  // 1/sqrt(96)

typedef unsigned short u16;
typedef short bf16x8 __attribute__((ext_vector_type(8)));
typedef unsigned short u16x8 __attribute__((ext_vector_type(8)));
typedef float f32x16 __attribute__((ext_vector_type(16)));

__device__ __forceinline__ u16 bfh(float x) {
  unsigned u = __float_as_uint(x);
  return (u16)((u + 0x7FFFu + ((u >> 16) & 1u)) >> 16);  // RNE bf16
}
__device__ __forceinline__ float bf2f(u16 h) {
  return __uint_as_float(((unsigned)h) << 16);
}

// ---------------------------------------------------------------------------
// Prep: pr = Wr*rgb, pd = Wd*dep; write psum = pr+pd (fp32 [b][c][n]) and
// transposed hi/lo bf16 operands prT2/pdT2[b][n][192] = [hi 96 | lo 96].
// grid (32 n-blocks, NB, 4 ch-quarters), block 128.
// ---------------------------------------------------------------------------
__launch_bounds__(128)
__global__ void k_prep(const float* __restrict__ rgb, const float* __restrict__ dep,
                       const float* __restrict__ Wr, const float* __restrict__ Wd,
                       float* __restrict__ psum, u16* __restrict__ prT2, u16* __restrict__ pdT2) {
  __shared__ float WrL[24][96];
  __shared__ float WdL[24][96];
  const int b = blockIdx.y, qo = blockIdx.z;
  const int n = blockIdx.x * 128 + threadIdx.x;
  for (int i = threadIdx.x; i < 24 * 96; i += 128) {
    WrL[i / 96][i % 96] = Wr[qo * 24 * 96 + i];
    WdL[i / 96][i % 96] = Wd[qo * 24 * 96 + i];
  }
  __syncthreads();
  float ar[24] = {}, ad[24] = {};
  const float* rp = rgb + (size_t)b * NC * HW + n;
  const float* dp = dep + (size_t)b * NC * HW + n;
  for (int c = 0; c < 96; ++c) {
    float xr = rp[(size_t)c * HW], xd = dp[(size_t)c * HW];
    #pragma unroll
    for (int o = 0; o < 24; ++o) {
      ar[o] = fmaf(WrL[o][c], xr, ar[o]);
      ad[o] = fmaf(WdL[o][c], xd, ad[o]);
    }
  }
  float* pso = psum + (size_t)b * NC * HW + (size_t)qo * 24 * HW + n;
  #pragma unroll
  for (int o = 0; o < 24; ++o) pso[(size_t)o * HW] = ar[o] + ad[o];

  u16* prow = prT2 + ((size_t)b * HW + n) * 192 + qo * 24;
  u16* drow = pdT2 + ((size_t)b * HW + n) * 192 + qo * 24;
  #pragma unroll
  for (int g = 0; g < 3; ++g) {
    u16x8 vh, vl, wh, wl;
    #pragma unroll
    for (int j = 0; j < 8; ++j) {
      float x = ar[g * 8 + j];
      u16 h = bfh(x); vh[j] = h; vl[j] = bfh(x - bf2f(h));
      float y = ad[g * 8 + j];
      u16 h2 = bfh(y); wh[j] = h2; wl[j] = bfh(y - bf2f(h2));
    }
    *(u16x8*)&prow[g * 8] = vh;
    *(u16x8*)&prow[96 + g * 8] = vl;
    *(u16x8*)&drow[g * 8] = wh;
    *(u16x8*)&drow[96 + g * 8] = wl;
  }
}

// ---------------------------------------------------------------------------
// MFMA energy pass. D[a][c] = sum_ch A[ch][a]*B[ch][c] via 3-term hi/lo bf16.
// Block tile: 128 A-rows x 256 B-cols, 4 waves (2x2), wave tile 64x128.
// PASS 0: A=pr(n) B=pd(m): colsum over n of exp(e*s)          -> zpart
// PASS 1: A=pd(m) B=pr(n): colsum over m of exp(e*s - lnZ[m]) -> spart
// K staged in 3 chunks of 32ch; LDS rows 128B [hi32|lo32], XOR-swizzled.
// ---------------------------------------------------------------------------
template <int PASS>
__launch_bounds__(256, 2)
__global__ void k_energy(const u16* __restrict__ At, const u16* __restrict__ Bt,
                         const float* __restrict__ nlz, float* __restrict__ part) {
  __shared__ u16 sA[128 * 64];
  __shared__ u16 sB[256 * 64];
  __shared__ float red[2][256];
  const int tid = threadIdx.x;
  const int lane = tid & 63, wid = tid >> 6;
  const int wA = wid >> 1, wB = wid & 1;
  const int b = blockIdx.z;
  const int a0 = blockIdx.y * 128;
  const int c0 = blockIdx.x * 256;
  const u16* Ab = At + ((size_t)b * HW + a0) * 192;
  const u16* Bb = Bt + ((size_t)b * HW + c0) * 192;

  f32x16 acc[2][4];
  #pragma unroll
  for (int ta = 0; ta < 2; ++ta)
    #pragma unroll
    for (int tb = 0; tb < 4; ++tb)
      #pragma unroll
      for (int q = 0; q < 16; ++q) acc[ta][tb][q] = 0.f;

  for (int ch = 0; ch < 3; ++ch) {
    const int k0 = ch * 32;
    if (ch) __syncthreads();
    // stage A (16KB) + B (32KB). LDS slot s=(row<<3)|phys; logical group
    // g = phys ^ (row&7); g<4 -> hi ch [k0+8g..), g>=4 -> lo.
    #pragma unroll
    for (int i = 0; i < 4; ++i) {
      int s = i * 256 + tid;
      int r = s >> 3;
      int g = (s & 7) ^ (r & 7);
      int soff = (g >> 2) * 96 + k0 + (g & 3) * 8;
      __builtin_amdgcn_global_load_lds(Ab + (size_t)r * 192 + soff, &sA[s * 8], 16, 0, 0);
    }
    #pragma unroll
    for (int i = 0; i < 8; ++i) {
      int s = i * 256 + tid;
      int r = s >> 3;
      int g = (s & 7) ^ (r & 7);
      int soff = (g >> 2) * 96 + k0 + (g & 3) * 8;
      __builtin_amdgcn_global_load_lds(Bb + (size_t)r * 192 + soff, &sB[s * 8], 16, 0, 0);
    }
    __syncthreads();
    #pragma unroll
    for (int ks = 0; ks < 2; ++ks) {
      bf16x8 ah[2], al[2];
      #pragma unroll
      for (int ta = 0; ta < 2; ++ta) {
        int r = wA * 64 + ta * 32 + (lane & 31);
        int gh = ks * 2 + (lane >> 5);
        ah[ta] = *(const bf16x8*)&sA[(r * 8 + (gh ^ (r & 7))) * 8];
        al[ta] = *(const bf16x8*)&sA[(r * 8 + ((gh + 4) ^ (r & 7))) * 8];
      }
      #pragma unroll
      for (int tb = 0; tb < 4; ++tb) {
        int r = wB * 128 + tb * 32 + (lane & 31);
        int gh = ks * 2 + (lane >> 5);
        bf16x8 bh = *(const bf16x8*)&sB[(r * 8 + (gh ^ (r & 7))) * 8];
        bf16x8 bl = *(const bf16x8*)&sB[(r * 8 + ((gh + 4) ^ (r & 7))) * 8];
        #pragma unroll
        for (int ta = 0; ta < 2; ++ta) {
          acc[ta][tb] = __builtin_amdgcn_mfma_f32_32x32x16_bf16(ah[ta], bh, acc[ta][tb], 0, 0, 0);
          acc[ta][tb] = __builtin_amdgcn_mfma_f32_32x32x16_bf16(al[ta], bh, acc[ta][tb], 0, 0, 0);
          acc[ta][tb] = __builtin_amdgcn_mfma_f32_32x32x16_bf16(ah[ta], bl, acc[ta][tb], 0, 0, 0);
        }
      }
    }
  }

  // exp + column sums (over A-rows). C/D: col=lane&31, row=(q&3)+8*(q>>2)+4*(lane>>5)
  float csum[4] = {0.f, 0.f, 0.f, 0.f};
  float nlzv = 0.f;
  if (PASS) nlzv = nlz[(size_t)b * HW + a0 + wA * 64 + lane];
  #pragma unroll
  for (int ta = 0; ta < 2; ++ta) {
    #pragma unroll
    for (int q = 0; q < 16; ++q) {
      float bias = 0.f;
      if (PASS) {
        int src = ta * 32 + (q & 3) + 8 * (q >> 2) + 4 * (lane >> 5);
        bias = __shfl(nlzv, src, 64);
      }
      #pragma unroll
      for (int tb = 0; tb < 4; ++tb)
        csum[tb] += __expf(fmaf(acc[ta][tb][q], SCALE_E, bias));
    }
  }
  #pragma unroll
  for (int tb = 0; tb < 4; ++tb) csum[tb] += __shfl_xor(csum[tb], 32, 64);
  if (lane < 32) {
    #pragma unroll
    for (int tb = 0; tb < 4; ++tb) red[wA][wB * 128 + tb * 32 + lane] = csum[tb];
  }
  __syncthreads();
  part[((size_t)blockIdx.y * NB + b) * HW + c0 + tid] = red[0][tid] + red[1][tid];
}

// ---------------------------------------------------------------------------
__global__ void k_zred(const float* __restrict__ zpart, float* __restrict__ nlz) {
  int idx = blockIdx.x * 256 + threadIdx.x;  // over NB*HW
  float s = 0.f;
  #pragma unroll
  for (int t = 0; t < 32; ++t) s += zpart[(size_t)t * (NB * HW) + idx];
  nlz[idx] = -logf(s);
}

__global__ void k_sred(const float* __restrict__ spart, float* __restrict__ sv) {
  int idx = blockIdx.x * 256 + threadIdx.x;
  float a = 0.f;
  #pragma unroll
  for (int t = 0; t < 32; ++t) a += spart[(size_t)t * (NB * HW) + idx];
  sv[idx] = a;
}

// ---------------------------------------------------------------------------
// gap[b,c] = (1/HW)*[ sum_n psum[c,n]*s[n] + sum_n (rgb+dep)[c,n] ]
// ---------------------------------------------------------------------------
__launch_bounds__(256)
__global__ void k_gap(const float* __restrict__ psum, const float* __restrict__ rgb,
                      const float* __restrict__ dep, const float* __restrict__ sv,
                      float* __restrict__ gap) {
  const int c = blockIdx.x, b = blockIdx.y;
  const size_t off = ((size_t)b * NC + c) * HW;
  const float* pp = psum + off;
  const float* rp = rgb + off;
  const float* dp = dep + off;
  const float* sp = sv + (size_t)b * HW;
  float a1 = 0.f, a2 = 0.f;
  for (int n = threadIdx.x * 4; n < HW; n += 1024) {
    float4 p = *(const float4*)&pp[n];
    float4 s4 = *(const float4*)&sp[n];
    float4 r4 = *(const float4*)&rp[n];
    float4 d4 = *(const float4*)&dp[n];
    a1 += p.x * s4.x + p.y * s4.y + p.z * s4.z + p.w * s4.w;
    a2 += (r4.x + d4.x) + (r4.y + d4.y) + (r4.z + d4.z) + (r4.w + d4.w);
  }
  #pragma unroll
  for (int o = 32; o > 0; o >>= 1) {
    a1 += __shfl_down(a1, o, 64);
    a2 += __shfl_down(a2, o, 64);
  }
  __shared__ float r1[4], r2[4];
  const int wv = threadIdx.x >> 6;
  if ((threadIdx.x & 63) == 0) { r1[wv] = a1; r2[wv] = a2; }
  __syncthreads();
  if (threadIdx.x == 0) {
    float t1 = r1[0] + r1[1] + r1[2] + r1[3];
    float t2 = r2[0] + r2[1] + r2[2] + r2[3];
    gap[b * NC + c] = (t1 + t2) * (1.0f / HW);
  }
}

// ---------------------------------------------------------------------------
// Tiny MLP + training-mode BatchNorm (over batch of 4) + ReLU, one block.
// ---------------------------------------------------------------------------
__launch_bounds__(256)
__global__ void k_mlp(const float* __restrict__ gap,
                      const float* __restrict__ Wm1, const float* __restrict__ g1,
                      const float* __restrict__ b1,
                      const float* __restrict__ Wm2, const float* __restrict__ g2,
                      const float* __restrict__ b2, float* __restrict__ out) {
  __shared__ float gl[NB * NC];
  __shared__ float h[NB * MID];
  __shared__ float h1r[NB * MID];
  __shared__ float h2[NB * NOUT];
  const int tid = threadIdx.x;
  for (int i = tid; i < NB * NC; i += 256) gl[i] = gap[i];
  __syncthreads();

  if (tid < NB * MID) {
    int b = tid / MID, j = tid % MID;
    float acc = 0.f;
    #pragma unroll
    for (int c = 0; c < NC; ++c) acc += gl[b * NC + c] * Wm1[j * NC + c];
    h[b * MID + j] = acc;
  }
  __syncthreads();

  if (tid < MID) {
    float x0 = h[0 * MID + tid], x1 = h[1 * MID + tid];
    float x2 = h[2 * MID + tid], x3 = h[3 * MID + tid];
    float mu = 0.25f * (x0 + x1 + x2 + x3);
    float d0 = x0 - mu, d1 = x1 - mu, d2 = x2 - mu, d3 = x3 - mu;
    float v = 0.25f * (d0 * d0 + d1 * d1 + d2 * d2 + d3 * d3);
    float sc = g1[tid] * rsqrtf(v + BEPS);
    float bb = b1[tid];
    h1r[0 * MID + tid] = fmaxf(d0 * sc + bb, 0.f);
    h1r[1 * MID + tid] = fmaxf(d1 * sc + bb, 0.f);
    h1r[2 * MID + tid] = fmaxf(d2 * sc + bb, 0.f);
    h1r[3 * MID + tid] = fmaxf(d3 * sc + bb, 0.f);
  }
  __syncthreads();

  for (int idx = tid; idx < NB * NOUT; idx += 256) {
    int b = idx >> 8, o = idx & 255;
    float acc = 0.f;
    #pragma unroll
    for (int j = 0; j < MID; ++j) acc += h1r[b * MID + j] * Wm2[o * MID + j];
    h2[b * NOUT + o] = acc;
  }
  __syncthreads();

  if (tid < NOUT) {
    float x0 = h2[0 * NOUT + tid], x1 = h2[1 * NOUT + tid];
    float x2 = h2[2 * NOUT + tid], x3 = h2[3 * NOUT + tid];
    float mu = 0.25f * (x0 + x1 + x2 + x3);
    float d0 = x0 - mu, d1 = x1 - mu, d2 = x2 - mu, d3 = x3 - mu;
    float v = 0.25f * (d0 * d0 + d1 * d1 + d2 * d2 + d3 * d3);
    float sc = g2[tid] * rsqrtf(v + BEPS);
    float bb = b2[tid];
    out[0 * NOUT + tid] = fmaxf(d0 * sc + bb, 0.f);
    out[1 * NOUT + tid] = fmaxf(d1 * sc + bb, 0.f);
    out[2 * NOUT + tid] = fmaxf(d2 * sc + bb, 0.f);
    out[3 * NOUT + tid] = fmaxf(d3 * sc + bb, 0.f);
  }
}

// ---------------------------------------------------------------------------
extern "C" void kernel_launch(void* const* d_in, const int* in_sizes, int n_in,
                              void* d_out, int out_size, void* d_ws, size_t ws_size,
                              hipStream_t stream) {
  const float* rgb   = (const float*)d_in[0];
  const float* dep   = (const float*)d_in[1];
  const float* Wd    = (const float*)d_in[2];
  const float* Wr    = (const float*)d_in[3];
  const float* Wm1   = (const float*)d_in[4];
  const float* bn1_g = (const float*)d_in[5];
  const float* bn1_b = (const float*)d_in[6];
  const float* Wm2   = (const float*)d_in[7];
  const float* bn2_g = (const float*)d_in[8];
  const float* bn2_b = (const float*)d_in[9];
  float* out = (float*)d_out;

  char* w = (char*)d_ws;
  u16* prT2 = (u16*)w;            w += (size_t)NB * HW * 192 * 2;   // 6.3 MB
  u16* pdT2 = (u16*)w;            w += (size_t)NB * HW * 192 * 2;   // 6.3 MB
  float* psum  = (float*)w;       w += (size_t)NB * NC * HW * 4;    // 6.3 MB
  float* zpart = (float*)w;       w += (size_t)32 * NB * HW * 4;    // 2 MB
  float* nlz   = (float*)w;       w += (size_t)NB * HW * 4;
  float* spart = (float*)w;       w += (size_t)32 * NB * HW * 4;    // 2 MB
  float* sv    = (float*)w;       w += (size_t)NB * HW * 4;
  float* gap   = (float*)w;       w += (size_t)NB * NC * 4;

  k_prep<<<dim3(HW / 128, NB, 4), 128, 0, stream>>>(rgb, dep, Wr, Wd, psum, prT2, pdT2);
  k_energy<0><<<dim3(HW / 256, HW / 128, NB), 256, 0, stream>>>(prT2, pdT2, nullptr, zpart);
  k_zred<<<NB * HW / 256, 256, 0, stream>>>(zpart, nlz);
  k_energy<1><<<dim3(HW / 256, HW / 128, NB), 256, 0, stream>>>(pdT2, prT2, nlz, spart);
  k_sred<<<NB * HW / 256, 256, 0, stream>>>(spart, sv);
  k_gap<<<dim3(NC, NB), 256, 0, stream>>>(psum, rgb, dep, sv, gap);
  k_mlp<<<1, 256, 0, stream>>>(gap, Wm1, bn1_g, bn1_b, Wm2, bn2_g, bn2_b, out);
}

// Round 4
// 134.907 us; speedup vs baseline: 4.3416x; 1.0541x over previous
//
#include <hip/hip_runtime.h>

#define HW 4096
#define NC 96
#define NB 4
#define MID 24
#define NOUT 256
#define BEPS 1e-5f
#define SCALE_E 0.10206207261596575f  // 1/sqrt(96)

typedef unsigned short u16;
typedef short bf16x8 __attribute__((ext_vector_type(8)));
typedef unsigned short u16x8 __attribute__((ext_vector_type(8)));
typedef float f32x16 __attribute__((ext_vector_type(16)));

__device__ __forceinline__ u16 bfh(float x) {
  unsigned u = __float_as_uint(x);
  return (u16)((u + 0x7FFFu + ((u >> 16) & 1u)) >> 16);  // RNE bf16
}
__device__ __forceinline__ float bf2f(u16 h) {
  return __uint_as_float(((unsigned)h) << 16);
}

// ---------------------------------------------------------------------------
// Prep: pr = Wr*rgb, pd = Wd*dep; psum = pr+pd fp32 [b][c][n]; transposed
// hi/lo bf16 rows prT2/pdT2[b][n][192] = [hi 96 | lo 96].
// grid (HW/64, NB, 4 o-quarters), block 256 = 32 n-slots(x2 via float2) x
// 4 wave-uniform o-groups of 6 o. Weights via scalar loads (uniform index).
// ---------------------------------------------------------------------------
__launch_bounds__(256)
__global__ void k_prep(const float* __restrict__ rgb, const float* __restrict__ dep,
                       const float* __restrict__ Wr, const float* __restrict__ Wd,
                       float* __restrict__ psum, u16* __restrict__ prT2, u16* __restrict__ pdT2) {
  __shared__ u16 buf[2][64][48];   // [arr][n-local][hi24|lo24] for this quarter
  const int tid = threadIdx.x;
  const int slot = tid & 31;                                   // n-pair slot
  const int og = __builtin_amdgcn_readfirstlane(tid >> 6);     // wave-uniform o-group
  const int b = blockIdx.y, q = blockIdx.z;
  const int n0 = blockIdx.x * 64;
  const int obase = q * 24 + og * 6;

  float ar[6][2], ad[6][2];
  #pragma unroll
  for (int o = 0; o < 6; ++o) { ar[o][0] = ar[o][1] = ad[o][0] = ad[o][1] = 0.f; }

  const float* rb = rgb + (size_t)b * NC * HW + n0;
  const float* db = dep + (size_t)b * NC * HW + n0;
  #pragma unroll 4
  for (int c = 0; c < NC; ++c) {
    float2 xr = ((const float2*)(rb + (size_t)c * HW))[slot];
    float2 xd = ((const float2*)(db + (size_t)c * HW))[slot];
    #pragma unroll
    for (int o = 0; o < 6; ++o) {
      float wr = Wr[(obase + o) * NC + c];   // uniform -> s_load
      float wd = Wd[(obase + o) * NC + c];
      ar[o][0] = fmaf(wr, xr.x, ar[o][0]);
      ar[o][1] = fmaf(wr, xr.y, ar[o][1]);
      ad[o][0] = fmaf(wd, xd.x, ad[o][0]);
      ad[o][1] = fmaf(wd, xd.y, ad[o][1]);
    }
  }

  // psum + pack hi/lo into LDS
  #pragma unroll
  for (int o = 0; o < 6; ++o) {
    float2 ps = make_float2(ar[o][0] + ad[o][0], ar[o][1] + ad[o][1]);
    *(float2*)&psum[((size_t)b * NC + obase + o) * HW + n0 + slot * 2] = ps;
    #pragma unroll
    for (int j = 0; j < 2; ++j) {
      int nl = slot * 2 + j;
      int ol = og * 6 + o;
      u16 h = bfh(ar[o][j]);
      buf[0][nl][ol] = h;
      buf[0][nl][24 + ol] = bfh(ar[o][j] - bf2f(h));
      u16 h2 = bfh(ad[o][j]);
      buf[1][nl][ol] = h2;
      buf[1][nl][24 + ol] = bfh(ad[o][j] - bf2f(h2));
    }
  }
  __syncthreads();

  // cooperative 16B-chunk writes: 2 arrays x 64 rows x (3 hi + 3 lo) chunks
  for (int ch = tid; ch < 768; ch += 256) {
    int arr = ch / 384;
    int r = ch % 384;
    int nl = r / 6, piece = r % 6;
    u16* dst = (arr ? pdT2 : prT2) + ((size_t)b * HW + n0 + nl) * 192 + q * 24;
    u16x8 v;
    if (piece < 3) {
      v = *(const u16x8*)&buf[arr][nl][piece * 8];
      *(u16x8*)&dst[piece * 8] = v;
    } else {
      v = *(const u16x8*)&buf[arr][nl][24 + (piece - 3) * 8];
      *(u16x8*)&dst[96 + (piece - 3) * 8] = v;
    }
  }
}

// ---------------------------------------------------------------------------
// MFMA energy pass. D[a][c] = sum_ch A[ch][a]*B[ch][c] via 3-term hi/lo bf16.
// Block tile: 128 A-rows x 256 B-cols, 4 waves (2x2), wave tile 64x128.
// PASS 0: A=pr(n) B=pd(m): colsum over n of exp(e*s)          -> zpart
// PASS 1: A=pd(m) B=pr(n): colsum over m of exp(e*s - lnZ[m]) -> spart
// K staged in 3 chunks of 32ch; LDS rows 128B [hi32|lo32], XOR-swizzled.
// ---------------------------------------------------------------------------
template <int PASS>
__launch_bounds__(256, 2)
__global__ void k_energy(const u16* __restrict__ At, const u16* __restrict__ Bt,
                         const float* __restrict__ nlz, float* __restrict__ part) {
  __shared__ u16 sA[128 * 64];
  __shared__ u16 sB[256 * 64];
  __shared__ float red[2][256];
  const int tid = threadIdx.x;
  const int lane = tid & 63, wid = tid >> 6;
  const int wA = wid >> 1, wB = wid & 1;
  const int b = blockIdx.z;
  const int a0 = blockIdx.y * 128;
  const int c0 = blockIdx.x * 256;
  const u16* Ab = At + ((size_t)b * HW + a0) * 192;
  const u16* Bb = Bt + ((size_t)b * HW + c0) * 192;

  f32x16 acc[2][4];
  #pragma unroll
  for (int ta = 0; ta < 2; ++ta)
    #pragma unroll
    for (int tb = 0; tb < 4; ++tb)
      #pragma unroll
      for (int q = 0; q < 16; ++q) acc[ta][tb][q] = 0.f;

  for (int ch = 0; ch < 3; ++ch) {
    const int k0 = ch * 32;
    if (ch) __syncthreads();
    #pragma unroll
    for (int i = 0; i < 4; ++i) {
      int s = i * 256 + tid;
      int r = s >> 3;
      int g = (s & 7) ^ (r & 7);
      int soff = (g >> 2) * 96 + k0 + (g & 3) * 8;
      __builtin_amdgcn_global_load_lds(Ab + (size_t)r * 192 + soff, &sA[s * 8], 16, 0, 0);
    }
    #pragma unroll
    for (int i = 0; i < 8; ++i) {
      int s = i * 256 + tid;
      int r = s >> 3;
      int g = (s & 7) ^ (r & 7);
      int soff = (g >> 2) * 96 + k0 + (g & 3) * 8;
      __builtin_amdgcn_global_load_lds(Bb + (size_t)r * 192 + soff, &sB[s * 8], 16, 0, 0);
    }
    __syncthreads();
    #pragma unroll
    for (int ks = 0; ks < 2; ++ks) {
      bf16x8 ah[2], al[2];
      #pragma unroll
      for (int ta = 0; ta < 2; ++ta) {
        int r = wA * 64 + ta * 32 + (lane & 31);
        int gh = ks * 2 + (lane >> 5);
        ah[ta] = *(const bf16x8*)&sA[(r * 8 + (gh ^ (r & 7))) * 8];
        al[ta] = *(const bf16x8*)&sA[(r * 8 + ((gh + 4) ^ (r & 7))) * 8];
      }
      #pragma unroll
      for (int tb = 0; tb < 4; ++tb) {
        int r = wB * 128 + tb * 32 + (lane & 31);
        int gh = ks * 2 + (lane >> 5);
        bf16x8 bh = *(const bf16x8*)&sB[(r * 8 + (gh ^ (r & 7))) * 8];
        bf16x8 bl = *(const bf16x8*)&sB[(r * 8 + ((gh + 4) ^ (r & 7))) * 8];
        #pragma unroll
        for (int ta = 0; ta < 2; ++ta) {
          acc[ta][tb] = __builtin_amdgcn_mfma_f32_32x32x16_bf16(ah[ta], bh, acc[ta][tb], 0, 0, 0);
          acc[ta][tb] = __builtin_amdgcn_mfma_f32_32x32x16_bf16(al[ta], bh, acc[ta][tb], 0, 0, 0);
          acc[ta][tb] = __builtin_amdgcn_mfma_f32_32x32x16_bf16(ah[ta], bl, acc[ta][tb], 0, 0, 0);
        }
      }
    }
  }

  // exp + column sums (over A-rows). C/D: col=lane&31, row=(q&3)+8*(q>>2)+4*(lane>>5)
  float csum[4] = {0.f, 0.f, 0.f, 0.f};
  float nlzv = 0.f;
  if (PASS) nlzv = nlz[(size_t)b * HW + a0 + wA * 64 + lane];
  #pragma unroll
  for (int ta = 0; ta < 2; ++ta) {
    #pragma unroll
    for (int q = 0; q < 16; ++q) {
      float bias = 0.f;
      if (PASS) {
        int src = ta * 32 + (q & 3) + 8 * (q >> 2) + 4 * (lane >> 5);
        bias = __shfl(nlzv, src, 64);
      }
      #pragma unroll
      for (int tb = 0; tb < 4; ++tb)
        csum[tb] += __expf(fmaf(acc[ta][tb][q], SCALE_E, bias));
    }
  }
  #pragma unroll
  for (int tb = 0; tb < 4; ++tb) csum[tb] += __shfl_xor(csum[tb], 32, 64);
  if (lane < 32) {
    #pragma unroll
    for (int tb = 0; tb < 4; ++tb) red[wA][wB * 128 + tb * 32 + lane] = csum[tb];
  }
  __syncthreads();
  part[((size_t)blockIdx.y * NB + b) * HW + c0 + tid] = red[0][tid] + red[1][tid];
}

// ---------------------------------------------------------------------------
__global__ void k_zred(const float* __restrict__ zpart, float* __restrict__ nlz) {
  int idx = blockIdx.x * 256 + threadIdx.x;  // over NB*HW
  float s = 0.f;
  #pragma unroll
  for (int t = 0; t < 32; ++t) s += zpart[(size_t)t * (NB * HW) + idx];
  nlz[idx] = -logf(s);
}

__global__ void k_sred(const float* __restrict__ spart, float* __restrict__ sv) {
  int idx = blockIdx.x * 256 + threadIdx.x;
  float a = 0.f;
  #pragma unroll
  for (int t = 0; t < 32; ++t) a += spart[(size_t)t * (NB * HW) + idx];
  sv[idx] = a;
}

// ---------------------------------------------------------------------------
// gap[b,c] = (1/HW)*[ sum_n psum[c,n]*s[n] + sum_n (rgb+dep)[c,n] ]
// ---------------------------------------------------------------------------
__launch_bounds__(256)
__global__ void k_gap(const float* __restrict__ psum, const float* __restrict__ rgb,
                      const float* __restrict__ dep, const float* __restrict__ sv,
                      float* __restrict__ gap) {
  const int c = blockIdx.x, b = blockIdx.y;
  const size_t off = ((size_t)b * NC + c) * HW;
  const float* pp = psum + off;
  const float* rp = rgb + off;
  const float* dp = dep + off;
  const float* sp = sv + (size_t)b * HW;
  float a1 = 0.f, a2 = 0.f;
  for (int n = threadIdx.x * 4; n < HW; n += 1024) {
    float4 p = *(const float4*)&pp[n];
    float4 s4 = *(const float4*)&sp[n];
    float4 r4 = *(const float4*)&rp[n];
    float4 d4 = *(const float4*)&dp[n];
    a1 += p.x * s4.x + p.y * s4.y + p.z * s4.z + p.w * s4.w;
    a2 += (r4.x + d4.x) + (r4.y + d4.y) + (r4.z + d4.z) + (r4.w + d4.w);
  }
  #pragma unroll
  for (int o = 32; o > 0; o >>= 1) {
    a1 += __shfl_down(a1, o, 64);
    a2 += __shfl_down(a2, o, 64);
  }
  __shared__ float r1[4], r2[4];
  const int wv = threadIdx.x >> 6;
  if ((threadIdx.x & 63) == 0) { r1[wv] = a1; r2[wv] = a2; }
  __syncthreads();
  if (threadIdx.x == 0) {
    float t1 = r1[0] + r1[1] + r1[2] + r1[3];
    float t2 = r2[0] + r2[1] + r2[2] + r2[3];
    gap[b * NC + c] = (t1 + t2) * (1.0f / HW);
  }
}

// ---------------------------------------------------------------------------
// Tiny MLP + training-mode BatchNorm (over batch of 4) + ReLU, one block.
// ---------------------------------------------------------------------------
__launch_bounds__(256)
__global__ void k_mlp(const float* __restrict__ gap,
                      const float* __restrict__ Wm1, const float* __restrict__ g1,
                      const float* __restrict__ b1,
                      const float* __restrict__ Wm2, const float* __restrict__ g2,
                      const float* __restrict__ b2, float* __restrict__ out) {
  __shared__ float gl[NB * NC];
  __shared__ float h[NB * MID];
  __shared__ float h1r[NB * MID];
  __shared__ float h2[NB * NOUT];
  const int tid = threadIdx.x;
  for (int i = tid; i < NB * NC; i += 256) gl[i] = gap[i];
  __syncthreads();

  if (tid < NB * MID) {
    int b = tid / MID, j = tid % MID;
    float acc = 0.f;
    #pragma unroll
    for (int c = 0; c < NC; ++c) acc += gl[b * NC + c] * Wm1[j * NC + c];
    h[b * MID + j] = acc;
  }
  __syncthreads();

  if (tid < MID) {
    float x0 = h[0 * MID + tid], x1 = h[1 * MID + tid];
    float x2 = h[2 * MID + tid], x3 = h[3 * MID + tid];
    float mu = 0.25f * (x0 + x1 + x2 + x3);
    float d0 = x0 - mu, d1 = x1 - mu, d2 = x2 - mu, d3 = x3 - mu;
    float v = 0.25f * (d0 * d0 + d1 * d1 + d2 * d2 + d3 * d3);
    float sc = g1[tid] * rsqrtf(v + BEPS);
    float bb = b1[tid];
    h1r[0 * MID + tid] = fmaxf(d0 * sc + bb, 0.f);
    h1r[1 * MID + tid] = fmaxf(d1 * sc + bb, 0.f);
    h1r[2 * MID + tid] = fmaxf(d2 * sc + bb, 0.f);
    h1r[3 * MID + tid] = fmaxf(d3 * sc + bb, 0.f);
  }
  __syncthreads();

  for (int idx = tid; idx < NB * NOUT; idx += 256) {
    int b = idx >> 8, o = idx & 255;
    float acc = 0.f;
    #pragma unroll
    for (int j = 0; j < MID; ++j) acc += h1r[b * MID + j] * Wm2[o * MID + j];
    h2[b * NOUT + o] = acc;
  }
  __syncthreads();

  if (tid < NOUT) {
    float x0 = h2[0 * NOUT + tid], x1 = h2[1 * NOUT + tid];
    float x2 = h2[2 * NOUT + tid], x3 = h2[3 * NOUT + tid];
    float mu = 0.25f * (x0 + x1 + x2 + x3);
    float d0 = x0 - mu, d1 = x1 - mu, d2 = x2 - mu, d3 = x3 - mu;
    float v = 0.25f * (d0 * d0 + d1 * d1 + d2 * d2 + d3 * d3);
    float sc = g2[tid] * rsqrtf(v + BEPS);
    float bb = b2[tid];
    out[0 * NOUT + tid] = fmaxf(d0 * sc + bb, 0.f);
    out[1 * NOUT + tid] = fmaxf(d1 * sc + bb, 0.f);
    out[2 * NOUT + tid] = fmaxf(d2 * sc + bb, 0.f);
    out[3 * NOUT + tid] = fmaxf(d3 * sc + bb, 0.f);
  }
}

// ---------------------------------------------------------------------------
extern "C" void kernel_launch(void* const* d_in, const int* in_sizes, int n_in,
                              void* d_out, int out_size, void* d_ws, size_t ws_size,
                              hipStream_t stream) {
  const float* rgb   = (const float*)d_in[0];
  const float* dep   = (const float*)d_in[1];
  const float* Wd    = (const float*)d_in[2];
  const float* Wr    = (const float*)d_in[3];
  const float* Wm1   = (const float*)d_in[4];
  const float* bn1_g = (const float*)d_in[5];
  const float* bn1_b = (const float*)d_in[6];
  const float* Wm2   = (const float*)d_in[7];
  const float* bn2_g = (const float*)d_in[8];
  const float* bn2_b = (const float*)d_in[9];
  float* out = (float*)d_out;

  char* w = (char*)d_ws;
  u16* prT2 = (u16*)w;            w += (size_t)NB * HW * 192 * 2;   // 6.3 MB
  u16* pdT2 = (u16*)w;            w += (size_t)NB * HW * 192 * 2;   // 6.3 MB
  float* psum  = (float*)w;       w += (size_t)NB * NC * HW * 4;    // 6.3 MB
  float* zpart = (float*)w;       w += (size_t)32 * NB * HW * 4;    // 2 MB
  float* nlz   = (float*)w;       w += (size_t)NB * HW * 4;
  float* spart = (float*)w;       w += (size_t)32 * NB * HW * 4;    // 2 MB
  float* sv    = (float*)w;       w += (size_t)NB * HW * 4;
  float* gap   = (float*)w;       w += (size_t)NB * NC * 4;

  k_prep<<<dim3(HW / 64, NB, 4), 256, 0, stream>>>(rgb, dep, Wr, Wd, psum, prT2, pdT2);
  k_energy<0><<<dim3(HW / 256, HW / 128, NB), 256, 0, stream>>>(prT2, pdT2, nullptr, zpart);
  k_zred<<<NB * HW / 256, 256, 0, stream>>>(zpart, nlz);
  k_energy<1><<<dim3(HW / 256, HW / 128, NB), 256, 0, stream>>>(pdT2, prT2, nlz, spart);
  k_sred<<<NB * HW / 256, 256, 0, stream>>>(spart, sv);
  k_gap<<<dim3(NC, NB), 256, 0, stream>>>(psum, rgb, dep, sv, gap);
  k_mlp<<<1, 256, 0, stream>>>(gap, Wm1, bn1_g, bn1_b, Wm2, bn2_g, bn2_b, out);
}